// Round 4
// baseline (276.185 us; speedup 1.0000x reference)
//
#include <hip/hip_runtime.h>
#include <stdint.h>

// Problem constants
#define S_LEN 2048
#define EMB   1024
#define NH    16
#define DK    64
#define BATCH 2
#define MTOT  (BATCH * S_LEN)  // 4096

typedef __attribute__((ext_vector_type(8))) short    short8;
typedef __attribute__((ext_vector_type(4))) float    f32x4;
typedef __attribute__((ext_vector_type(4))) float    float4v;
typedef __attribute__((ext_vector_type(4))) unsigned uint4v;
typedef __attribute__((ext_vector_type(2))) unsigned uint2v;

__device__ __forceinline__ short f2b(float f) {
  unsigned u = __builtin_bit_cast(unsigned, f);
  u = (u + 0x7FFFu + ((u >> 16) & 1u)) >> 16;  // RNE to bf16
  return (short)u;
}
// pack two f32 -> two bf16 in one uint (low = a, high = b)
__device__ __forceinline__ unsigned cvt2(float a, float b) {
  unsigned r;
  asm("v_cvt_pk_bf16_f32 %0, %1, %2" : "=v"(r) : "v"(a), "v"(b));
  return r;
}

// ---------------------------------------------------------------------------
// f32 -> bf16 bulk convert (weights pre-pass). n4 = count/4.
// ---------------------------------------------------------------------------
__global__ __launch_bounds__(256) void cvt_f32_bf16(const float* __restrict__ src,
                                                    short* __restrict__ dst, int n4)
{
  const int i = blockIdx.x * blockDim.x + threadIdx.x;
  if (i < n4) {
    const f32x4 v = *(const f32x4*)(src + (size_t)i * 4);
    uint2v p;
    p[0] = cvt2(v[0], v[1]);
    p[1] = cvt2(v[2], v[3]);
    *(uint2v*)(dst + (size_t)i * 4) = p;
  }
}

// ---------------------------------------------------------------------------
// NT GEMM: C(M x N) = A(M x K) * W(N x K)^T + bias. M=4096, N=1024, K=1024.
// W is bf16 (pre-converted). Tile 128x64, BK=64, 256 threads (4 waves, 2x2).
// LDS k-chunk-major: [chunk(8)][row][4 uints] -> each MFMA fragment is one
// contiguous 16B ds_read_b128 per lane. All LDS accesses unsigned-typed.
// MODE 0: A = f32 (converted to bf16 in staging); out = bf16 scattered to
//         (B,H,S,DK), scale applied after bias.
// MODE 1: A = bf16; out = f32 row-major (M,N).
// ---------------------------------------------------------------------------
template <int MODE>
__global__ __launch_bounds__(256) void gemm_nt(const void* __restrict__ Av,
                                               const short* __restrict__ W,
                                               const float* __restrict__ bias,
                                               void* __restrict__ outv,
                                               float scale)
{
  __shared__ __align__(16) unsigned Au[8][128][4];  // 16 KB
  __shared__ __align__(16) unsigned Bu[8][64][4];   //  8 KB
  const int tid = threadIdx.x;
  const int w = tid >> 6, l = tid & 63;
  const int g = l >> 4, r16 = l & 15;
  const int m0 = blockIdx.y * 128, n0 = blockIdx.x * 64;
  const int wr = w >> 1, wc = w & 1;       // wave tile 64x32 at (wr*64, wc*32)
  const int srow = tid >> 3, shc = tid & 7;

  float4v acc[4][2];
#pragma unroll
  for (int i = 0; i < 4; ++i)
#pragma unroll
    for (int j = 0; j < 2; ++j)
      acc[i][j] = (float4v){0.f, 0.f, 0.f, 0.f};

  const float* Af = (const float*)Av + (size_t)m0 * EMB;
  const short* Ab = (const short*)Av + (size_t)m0 * EMB;
  const short* Wbase = W + (size_t)n0 * EMB;

  for (int k0 = 0; k0 < EMB; k0 += 64) {
    uint4v apk[4], bpk[2];
    if constexpr (MODE == 0) {
#pragma unroll
      for (int p = 0; p < 4; ++p) {
        const float* src = Af + (size_t)(p * 32 + srow) * EMB + k0 + shc * 8;
        const f32x4 x = *(const f32x4*)src;
        const f32x4 y = *(const f32x4*)(src + 4);
        apk[p][0] = cvt2(x[0], x[1]);
        apk[p][1] = cvt2(x[2], x[3]);
        apk[p][2] = cvt2(y[0], y[1]);
        apk[p][3] = cvt2(y[2], y[3]);
      }
    } else {
#pragma unroll
      for (int p = 0; p < 4; ++p)
        apk[p] = __builtin_bit_cast(uint4v,
            *(const short8*)(Ab + (size_t)(p * 32 + srow) * EMB + k0 + shc * 8));
    }
#pragma unroll
    for (int p = 0; p < 2; ++p)
      bpk[p] = __builtin_bit_cast(uint4v,
          *(const short8*)(Wbase + (size_t)(p * 32 + srow) * EMB + k0 + shc * 8));

    __syncthreads();
#pragma unroll
    for (int p = 0; p < 4; ++p)
      *(uint4v*)&Au[shc][p * 32 + srow][0] = apk[p];
#pragma unroll
    for (int p = 0; p < 2; ++p)
      *(uint4v*)&Bu[shc][p * 32 + srow][0] = bpk[p];
    __syncthreads();

#pragma unroll
    for (int ks = 0; ks < 2; ++ks) {
      const int c = ks * 4 + g;
      short8 af[4], bf[2];
#pragma unroll
      for (int i = 0; i < 4; ++i)
        af[i] = __builtin_bit_cast(short8, *(const uint4v*)&Au[c][wr * 64 + i * 16 + r16][0]);
#pragma unroll
      for (int j = 0; j < 2; ++j)
        bf[j] = __builtin_bit_cast(short8, *(const uint4v*)&Bu[c][wc * 32 + j * 16 + r16][0]);
#pragma unroll
      for (int i = 0; i < 4; ++i)
#pragma unroll
        for (int j = 0; j < 2; ++j)
          acc[i][j] = __builtin_amdgcn_mfma_f32_16x16x32_bf16(af[i], bf[j], acc[i][j], 0, 0, 0);
    }
  }

  // Epilogue: C/D layout is col = l&15, row = (l>>4)*4 + r
#pragma unroll
  for (int j = 0; j < 2; ++j) {
    const int n = n0 + wc * 32 + j * 16 + r16;
    const float bv = bias[n];
#pragma unroll
    for (int i = 0; i < 4; ++i) {
#pragma unroll
      for (int r = 0; r < 4; ++r) {
        const int m = m0 + wr * 64 + i * 16 + g * 4 + r;
        const float vv = (acc[i][j][r] + bv) * scale;
        if constexpr (MODE == 0) {
          const int b = m >> 11, s = m & (S_LEN - 1);
          const int h = n >> 6, d = n & (DK - 1);
          ((short*)outv)[(size_t)((b * NH + h) * S_LEN + s) * DK + d] = f2b(vv);
        } else {
          ((float*)outv)[(size_t)m * EMB + n] = vv;
        }
      }
    }
  }
}

// ---------------------------------------------------------------------------
// Flash attention (bf16 in/out, f32 softmax+acc). Grid: (S/64, B*H).
// Block 256 = 4 waves, wave handles 16 q rows. Swapped QK^T: S^T =
// mfma(K_frag, Q_frag) -> lane holds q = l&15, kv = (l>>4)*4 + r. Softmax
// reduce = in-lane + shfl_xor 16/32. P and V^T in LDS as unsigned arrays,
// all RAW barrier-separated. Scores pre-scaled via Q projection (x0.125).
// ---------------------------------------------------------------------------
__global__ __launch_bounds__(256) void attn_kernel(const short* __restrict__ Qp,
                                                   const short* __restrict__ Kp,
                                                   const short* __restrict__ Vp,
                                                   short* __restrict__ ctx)
{
  __shared__ __align__(16) unsigned Vtu[64][36];     // V^T tile [d][kv pair]
  __shared__ __align__(16) unsigned Plu[4][16][36];  // per-wave P [q][kv pair]
  const int tid = threadIdx.x;
  const int w = tid >> 6, l = tid & 63;
  const int g = l >> 4, r16 = l & 15;
  const int bh = blockIdx.y;                       // b*NH + h
  const int q0 = blockIdx.x * 64 + w * 16;
  const short* Qb = Qp + (size_t)bh * S_LEN * DK;
  const short* Kb = Kp + (size_t)bh * S_LEN * DK;
  const short* Vb = Vp + (size_t)bh * S_LEN * DK;

  const short8 qf0 = *(const short8*)(Qb + (size_t)(q0 + r16) * DK + g * 8);
  const short8 qf1 = *(const short8*)(Qb + (size_t)(q0 + r16) * DK + 32 + g * 8);

  float4v oacc[4];
#pragma unroll
  for (int j = 0; j < 4; ++j) oacc[j] = (float4v){0.f, 0.f, 0.f, 0.f};
  float m_run = -3.0e38f, l_run = 0.f;

  const int vkvp = tid >> 3;         // 0..31: kv pair
  const int vdc  = (tid & 7) * 8;    // d chunk base

  for (int kv0 = 0; kv0 < S_LEN; kv0 += 64) {
    const short8 v0 = *(const short8*)(Vb + (size_t)(kv0 + 2 * vkvp) * DK + vdc);
    const short8 v1 = *(const short8*)(Vb + (size_t)(kv0 + 2 * vkvp + 1) * DK + vdc);
    __syncthreads();  // prior iteration's Vtu reads complete
#pragma unroll
    for (int i = 0; i < 8; ++i) {
      unsigned pk = ((unsigned)(unsigned short)v0[i]) |
                    (((unsigned)(unsigned short)v1[i]) << 16);
      Vtu[vdc + i][vkvp] = pk;
    }
    __syncthreads();

    // --- S^T = K * Q^T for four 16-kv subtiles ---
    float4v st[4];
#pragma unroll
    for (int s = 0; s < 4; ++s) {
      const short8 kf0 = *(const short8*)(Kb + (size_t)(kv0 + s * 16 + r16) * DK + g * 8);
      const short8 kf1 = *(const short8*)(Kb + (size_t)(kv0 + s * 16 + r16) * DK + 32 + g * 8);
      float4v a = (float4v){0.f, 0.f, 0.f, 0.f};
      a = __builtin_amdgcn_mfma_f32_16x16x32_bf16(kf0, qf0, a, 0, 0, 0);
      a = __builtin_amdgcn_mfma_f32_16x16x32_bf16(kf1, qf1, a, 0, 0, 0);
      st[s] = a;
    }

    // --- online softmax (per lane: q = l&15, 16 kv values) ---
    float mt = -3.0e38f;
#pragma unroll
    for (int s = 0; s < 4; ++s)
#pragma unroll
      for (int r = 0; r < 4; ++r) mt = fmaxf(mt, st[s][r]);
    mt = fmaxf(mt, __shfl_xor(mt, 16));
    mt = fmaxf(mt, __shfl_xor(mt, 32));
    const float m_new = fmaxf(m_run, mt);
    const float alpha = __expf(m_run - m_new);
    float psum = 0.f;
#pragma unroll
    for (int s = 0; s < 4; ++s)
#pragma unroll
      for (int r = 0; r < 4; ++r) {
        const float p = __expf(st[s][r] - m_new);
        st[s][r] = p;
        psum += p;
      }
    l_run = l_run * alpha + psum;
    m_run = m_new;

    // --- P -> LDS (bf16 pairs) ---
#pragma unroll
    for (int s = 0; s < 4; ++s) {
      const unsigned p01 = (unsigned)(unsigned short)f2b(st[s][0]) |
                           ((unsigned)(unsigned short)f2b(st[s][1]) << 16);
      const unsigned p23 = (unsigned)(unsigned short)f2b(st[s][2]) |
                           ((unsigned)(unsigned short)f2b(st[s][3]) << 16);
      Plu[w][r16][s * 8 + g * 2]     = p01;
      Plu[w][r16][s * 8 + g * 2 + 1] = p23;
    }
    __syncthreads();  // P visible before PV reads

    // --- rescale O by alpha ---
    const float ar0 = __shfl(alpha, g * 4 + 0);
    const float ar1 = __shfl(alpha, g * 4 + 1);
    const float ar2 = __shfl(alpha, g * 4 + 2);
    const float ar3 = __shfl(alpha, g * 4 + 3);
#pragma unroll
    for (int j = 0; j < 4; ++j) {
      oacc[j][0] *= ar0; oacc[j][1] *= ar1;
      oacc[j][2] *= ar2; oacc[j][3] *= ar3;
    }

    // --- PV: O += P(16x64) * V(64x64) ---
#pragma unroll
    for (int kc = 0; kc < 2; ++kc) {
      const short8 pf = __builtin_bit_cast(short8, *(const uint4v*)&Plu[w][r16][kc * 16 + g * 4]);
#pragma unroll
      for (int j = 0; j < 4; ++j) {
        const short8 vf = __builtin_bit_cast(short8, *(const uint4v*)&Vtu[j * 16 + r16][kc * 16 + g * 4]);
        oacc[j] = __builtin_amdgcn_mfma_f32_16x16x32_bf16(pf, vf, oacc[j], 0, 0, 0);
      }
    }
  }

  // --- finalize ---
  float lt = l_run + __shfl_xor(l_run, 16);
  lt = lt + __shfl_xor(lt, 32);
  const float li0 = 1.f / __shfl(lt, g * 4 + 0);
  const float li1 = 1.f / __shfl(lt, g * 4 + 1);
  const float li2 = 1.f / __shfl(lt, g * 4 + 2);
  const float li3 = 1.f / __shfl(lt, g * 4 + 3);
  const int b = bh >> 4, h = bh & 15;
#pragma unroll
  for (int j = 0; j < 4; ++j) {
    const int d = h * DK + j * 16 + r16;
    const int qr = q0 + g * 4;
    ctx[(size_t)(b * S_LEN + qr + 0) * EMB + d] = f2b(oacc[j][0] * li0);
    ctx[(size_t)(b * S_LEN + qr + 1) * EMB + d] = f2b(oacc[j][1] * li1);
    ctx[(size_t)(b * S_LEN + qr + 2) * EMB + d] = f2b(oacc[j][2] * li2);
    ctx[(size_t)(b * S_LEN + qr + 3) * EMB + d] = f2b(oacc[j][3] * li3);
  }
}

// ---------------------------------------------------------------------------
extern "C" void kernel_launch(void* const* d_in, const int* in_sizes, int n_in,
                              void* d_out, int out_size, void* d_ws, size_t ws_size,
                              hipStream_t stream)
{
  const float* q  = (const float*)d_in[0];
  const float* k  = (const float*)d_in[1];
  const float* v  = (const float*)d_in[2];
  const float* Wq = (const float*)d_in[3];
  const float* bq = (const float*)d_in[4];
  const float* Wk = (const float*)d_in[5];
  const float* bk = (const float*)d_in[6];
  const float* Wv = (const float*)d_in[7];
  const float* bv = (const float*)d_in[8];
  const float* Wo = (const float*)d_in[9];
  const float* bo = (const float*)d_in[10];

  short* ws = (short*)d_ws;
  const size_t WSZ  = (size_t)EMB * EMB;   // 1M elems per weight matrix
  const size_t PROJ = (size_t)MTOT * EMB;  // 4M elems per activation
  short* Wqb = ws;                 // bf16 weights: 4 x 2 MB
  short* Wkb = ws + WSZ;
  short* Wvb = ws + 2 * WSZ;
  short* Wob = ws + 3 * WSZ;
  short* Qp  = ws + 4 * WSZ;       // (B,H,S,DK) bf16, pre-scaled by 1/8
  short* Vp  = Qp + PROJ;
  short* Cx  = Vp + PROJ;          // (B*S, E) bf16 context
  short* Kp  = (short*)d_out;      // K parks in d_out (8.4 MB bf16 in 16.8 MB
                                   // f32 buffer); consumed before final GEMM.

  const int n4 = (int)(WSZ / 4);
  dim3 cg((n4 + 255) / 256), cb(256);
  cvt_f32_bf16<<<cg, cb, 0, stream>>>(Wq, Wqb, n4);
  cvt_f32_bf16<<<cg, cb, 0, stream>>>(Wk, Wkb, n4);
  cvt_f32_bf16<<<cg, cb, 0, stream>>>(Wv, Wvb, n4);
  cvt_f32_bf16<<<cg, cb, 0, stream>>>(Wo, Wob, n4);

  dim3 gb(EMB / 64, MTOT / 128), tb(256);
  gemm_nt<0><<<gb, tb, 0, stream>>>(q, Wqb, bq, Qp, 0.125f);  // scale folded
  gemm_nt<0><<<gb, tb, 0, stream>>>(k, Wkb, bk, Kp, 1.0f);
  gemm_nt<0><<<gb, tb, 0, stream>>>(v, Wvb, bv, Vp, 1.0f);
  attn_kernel<<<dim3(S_LEN / 64, BATCH * NH), tb, 0, stream>>>(Qp, Kp, Vp, Cx);
  gemm_nt<1><<<gb, tb, 0, stream>>>(Cx, Wob, bo, d_out, 1.0f);
}